// Round 1
// baseline (615.687 us; speedup 1.0000x reference)
//
#include <hip/hip_runtime.h>

#define IDIM 384
#define SDIM 2048
#define NCH  8
#define CHUNK 256

// workspace layout (float offsets)
#define WS_STATS 0                                  // [I][S][2]  (mu, rstd)
#define WS_QGP   (IDIM*SDIM*2)                      // [I][NCH][65] (qg partial + count)
#define WS_Q     (WS_QGP + IDIM*NCH*65)             // [I][64]   scaled q
#define WS_ATT   (WS_Q + IDIM*64)                   // [I][NCH][8][10] (m,l,ctx[8])
#define WS_CTX   (WS_ATT + IDIM*NCH*8*10)           // [I][64]
#define WS_WGT   (WS_CTX + IDIM*64)                 // [64][64]  WgS[c][j] = Wg[j][c]
#define WS_WOT   (WS_WGT + 64*64)                   // [64][64]  WoS[j][cc] = Wo[cc][j]

typedef float f16v __attribute__((ext_vector_type(16)));

// ---------------- Kernel W: pre-transpose Wg, Wo for scalar-b GEMMs --------
__global__ __launch_bounds__(64) void kW(const float* __restrict__ Wg,
                                         const float* __restrict__ Wo,
                                         float* __restrict__ ws) {
    int a = blockIdx.x, t = threadIdx.x;
    ws[WS_WGT + a * 64 + t] = Wg[t * 64 + a];   // WgS[c=a][j=t] = Wg[j][c]
    ws[WS_WOT + a * 64 + t] = Wo[t * 64 + a];   // WoS[j=a][cc=t] = Wo[cc][j]
}

// ---------------- Kernel A: LN stats + q_global partials -------------------
// 8 lanes per row (each sums 8 contiguous elems) -> 3 shuffles per row
// instead of one wave per row with 12 shuffles. Stats written coalesced.
__global__ __launch_bounds__(256) void kA(const float* __restrict__ m,
                                          const float* __restrict__ mask,
                                          const float* __restrict__ gamma,
                                          const float* __restrict__ beta,
                                          float* __restrict__ ws) {
    int bx = blockIdx.x;
    int i = bx >> 3, chk = bx & 7;
    int tid = threadIdx.x;
    int rg = tid >> 3;      // 0..31 row-group within 32-row tile
    int c8 = tid & 7;       // which 8-element channel slice
    float4 ga4 = *(const float4*)&gamma[c8 * 8];
    float4 gb4 = *(const float4*)&gamma[c8 * 8 + 4];
    float4 ba4 = *(const float4*)&beta[c8 * 8];
    float4 bb4 = *(const float4*)&beta[c8 * 8 + 4];
    float g[8] = {ga4.x, ga4.y, ga4.z, ga4.w, gb4.x, gb4.y, gb4.z, gb4.w};
    float b[8] = {ba4.x, ba4.y, ba4.z, ba4.w, bb4.x, bb4.y, bb4.z, bb4.w};
    float qg[8];
    #pragma unroll
    for (int j = 0; j < 8; ++j) qg[j] = 0.f;
    float cnt = 0.f;
    float* stats = ws + WS_STATS;

    for (int t = 0; t < 8; ++t) {
        int s = chk * CHUNK + t * 32 + rg;
        const float* mp = &m[((size_t)s * IDIM + i) * 64 + c8 * 8];
        float4 xa = *(const float4*)mp;
        float4 xb = *(const float4*)(mp + 4);
        float x[8] = {xa.x, xa.y, xa.z, xa.w, xb.x, xb.y, xb.z, xb.w};
        float sx = 0.f, sxx = 0.f;
        #pragma unroll
        for (int j = 0; j < 8; ++j) { sx += x[j]; sxx += x[j] * x[j]; }
        sx += __shfl_xor(sx, 1); sxx += __shfl_xor(sxx, 1);
        sx += __shfl_xor(sx, 2); sxx += __shfl_xor(sxx, 2);
        sx += __shfl_xor(sx, 4); sxx += __shfl_xor(sxx, 4);
        float mu  = sx * (1.f / 64.f);
        float var = sxx * (1.f / 64.f) - mu * mu;
        float rs  = rsqrtf(var + 1e-5f);
        float mk  = mask[s * IDIM + i];
        #pragma unroll
        for (int j = 0; j < 8; ++j) {
            float mn = (x[j] - mu) * rs * g[j] + b[j];
            qg[j] += mk * mn;
        }
        if (c8 == 0) {
            cnt += mk;
            float2 st = {mu, rs};
            *(float2*)&stats[((size_t)i * SDIM + s) * 2] = st;  // 8 lanes/wave -> 64B coalesced
        }
    }
    __shared__ float red[32][68];
    #pragma unroll
    for (int j = 0; j < 8; ++j) red[rg][c8 * 8 + j] = qg[j];
    if (c8 == 0) red[rg][64] = cnt;
    __syncthreads();
    if (tid < 65) {
        float v = 0.f;
        #pragma unroll
        for (int r = 0; r < 32; ++r) v += red[r][tid];
        ws[WS_QGP + (i * NCH + chk) * 65 + tid] = v;
    }
}

// ---------------- Kernel B: reduce q_global, compute q = (qg @ WqT)/sqrt(8) -
__global__ __launch_bounds__(64) void kB(const float* __restrict__ Wq,
                                         float* __restrict__ ws) {
    int i = blockIdx.x, l = threadIdx.x;
    float sum = 0.f, cnt = 0.f;
    #pragma unroll
    for (int c = 0; c < NCH; ++c) {
        sum += ws[WS_QGP + (i * NCH + c) * 65 + l];
        cnt += ws[WS_QGP + (i * NCH + c) * 65 + 64];
    }
    float denom = fmaxf(cnt, 1e-5f);
    __shared__ float qg[64];
    qg[l] = sum / denom;
    __syncthreads();
    float acc = 0.f;
    #pragma unroll 8
    for (int c = 0; c < 64; ++c) acc += qg[c] * Wq[l * 64 + c];
    ws[WS_Q + i * 64 + l] = acc * 0.35355339059327373f;  // fold in 1/sqrt(CH)
}

// ---------------- Kernel C: k/v + flash-softmax partials per chunk ---------
__global__ __launch_bounds__(256) void kC(const float* __restrict__ m,
                                          const float* __restrict__ mask,
                                          const float* __restrict__ gamma,
                                          const float* __restrict__ beta,
                                          const float* __restrict__ Wk,
                                          const float* __restrict__ Wv,
                                          float* __restrict__ ws) {
    int bx = blockIdx.x;
    int i = bx >> 3, chk = bx & 7;
    int tid = threadIdx.x;
    __shared__ float mnT[32 * 68];
    __shared__ float Wk_s[8 * 68], Wv_s[8 * 68];
    __shared__ float k_s[32 * 9], v_s[32 * 9];
    __shared__ float q_s[64];
    __shared__ float red[32 * 8 * 10];
    const float* stats = ws + WS_STATS;

    if (tid < 64) q_s[tid] = ws[WS_Q + i * 64 + tid];
    for (int idx = tid; idx < 512; idx += 256) {
        int r = idx >> 6, c = idx & 63;
        Wk_s[r * 68 + c] = Wk[idx];
        Wv_s[r * 68 + c] = Wv[idx];
    }

    int sr = tid >> 3;   // 0..31
    int lo = tid & 7;    // ch (phase 2) or h (phase 3)
    float m_run = -1e30f, l_run = 0.f, ctx[8];
    #pragma unroll
    for (int z = 0; z < 8; ++z) ctx[z] = 0.f;
    __syncthreads();

    for (int t = 0; t < 8; ++t) {
        int sbase = chk * CHUNK + t * 32;
        // stage m_norm tile (recompute LN from stored stats)
        for (int idx = tid; idx < 512; idx += 256) {
            int r = idx >> 4, c4 = idx & 15;
            int s = sbase + r;
            float4 x4 = *(const float4*)&m[((size_t)s * IDIM + i) * 64 + c4 * 4];
            float4 g4 = *(const float4*)&gamma[c4 * 4];
            float4 b4 = *(const float4*)&beta[c4 * 4];
            float2 st = *(const float2*)&stats[((size_t)i * SDIM + s) * 2];
            float4 mn;
            mn.x = (x4.x - st.x) * st.y * g4.x + b4.x;
            mn.y = (x4.y - st.x) * st.y * g4.y + b4.y;
            mn.z = (x4.z - st.x) * st.y * g4.z + b4.z;
            mn.w = (x4.w - st.x) * st.y * g4.w + b4.w;
            *(float4*)&mnT[r * 68 + c4 * 4] = mn;
        }
        __syncthreads();
        // k, v : [32 rows][8 ch]
        {
            float accK = 0.f, accV = 0.f;
            #pragma unroll
            for (int c4 = 0; c4 < 16; ++c4) {
                float4 a  = *(const float4*)&mnT[sr * 68 + c4 * 4];
                float4 wk = *(const float4*)&Wk_s[lo * 68 + c4 * 4];
                float4 wv = *(const float4*)&Wv_s[lo * 68 + c4 * 4];
                accK += a.x * wk.x + a.y * wk.y + a.z * wk.z + a.w * wk.w;
                accV += a.x * wv.x + a.y * wv.y + a.z * wv.z + a.w * wv.w;
            }
            k_s[sr * 9 + lo] = accK;
            v_s[sr * 9 + lo] = accV;
        }
        __syncthreads();
        // online softmax update: thread = (row sr, head lo)
        {
            float lg = 0.f;
            #pragma unroll
            for (int c = 0; c < 8; ++c) lg += q_s[lo * 8 + c] * k_s[sr * 9 + c];
            float mk = mask[(sbase + sr) * IDIM + i];
            lg = (mk > 0.f) ? lg : -1e9f;
            float mnew = fmaxf(m_run, lg);
            float al = expf(m_run - mnew);
            float p  = expf(lg - mnew);
            l_run = l_run * al + p;
            #pragma unroll
            for (int c = 0; c < 8; ++c) ctx[c] = ctx[c] * al + p * v_s[sr * 9 + c];
            m_run = mnew;
        }
        __syncthreads();
    }
    // merge the 32 row-threads per head
    int base = (sr * 8 + lo) * 10;
    red[base] = m_run; red[base + 1] = l_run;
    #pragma unroll
    for (int c = 0; c < 8; ++c) red[base + 2 + c] = ctx[c];
    __syncthreads();
    if (tid < 8) {
        int h = tid;
        float M = -1e30f;
        for (int r = 0; r < 32; ++r) M = fmaxf(M, red[(r * 8 + h) * 10]);
        float L = 0.f, CT[8];
        #pragma unroll
        for (int c = 0; c < 8; ++c) CT[c] = 0.f;
        for (int r = 0; r < 32; ++r) {
            float e = expf(red[(r * 8 + h) * 10] - M);
            L += red[(r * 8 + h) * 10 + 1] * e;
            for (int c = 0; c < 8; ++c) CT[c] += red[(r * 8 + h) * 10 + 2 + c] * e;
        }
        float* dst = ws + WS_ATT + ((i * NCH + chk) * 8 + h) * 10;
        dst[0] = M; dst[1] = L;
        for (int c = 0; c < 8; ++c) dst[2 + c] = CT[c];
    }
}

// ---------------- Kernel D: merge chunk partials -> ctx --------------------
__global__ __launch_bounds__(64) void kD(float* __restrict__ ws) {
    int i = blockIdx.x, l = threadIdx.x;
    int h = l >> 3, c2 = l & 7;
    float M = -1e30f;
    #pragma unroll
    for (int c = 0; c < NCH; ++c)
        M = fmaxf(M, ws[WS_ATT + ((i * NCH + c) * 8 + h) * 10]);
    float L = 0.f, CT = 0.f;
    #pragma unroll
    for (int c = 0; c < NCH; ++c) {
        const float* src = ws + WS_ATT + ((i * NCH + c) * 8 + h) * 10;
        float e = expf(src[0] - M);
        L += src[1] * e;
        CT += src[2 + c2] * e;
    }
    ws[WS_CTX + i * 64 + l] = CT / L;
}

// ---------------- Kernel E: g = sigmoid(mn@WgT+bg); out=(ctx*g)@WoT+bo -----
// Wave-slab GEMM: each wave owns 16 output columns; the b-operand slice is
// wave-uniform -> scalar (s_load_dwordx16) from the pre-transposed copies in
// ws. Removes the 32-way-redundant LDS b reads that made the old kE
// LDS-throughput-bound. a-operand: 2 rows/lane (l, l+64) via ds_read_b128.
__global__ __launch_bounds__(256, 4) void kE(const float* __restrict__ m,
                                             const float* __restrict__ gamma,
                                             const float* __restrict__ beta,
                                             const float* __restrict__ bg,
                                             const float* __restrict__ bo,
                                             const float* __restrict__ ws,
                                             float* __restrict__ out) {
    int bx = blockIdx.x;
    int i = bx >> 4;        // 16 tiles of 128 rows per column
    int tile = bx & 15;
    int tid = threadIdx.x;
    int l = tid & 63;
    int wv16 = __builtin_amdgcn_readfirstlane((tid >> 6) << 4);  // wave's col base
    __shared__ float mnT[128 * 68];     // m_norm tile, later o tile, then out tile
    const float* stats = ws + WS_STATS;
    int s0 = tile * 128;

    // wave-uniform per-column vectors (compiler keeps these scalar)
    float ctxv[16], bgv[16], bov[16];
    #pragma unroll
    for (int q = 0; q < 4; ++q) {
        float4 cv = *(const float4*)&ws[WS_CTX + i * 64 + wv16 + q * 4];
        float4 gv = *(const float4*)&bg[wv16 + q * 4];
        float4 ov = *(const float4*)&bo[wv16 + q * 4];
        ctxv[q*4+0]=cv.x; ctxv[q*4+1]=cv.y; ctxv[q*4+2]=cv.z; ctxv[q*4+3]=cv.w;
        bgv[q*4+0]=gv.x;  bgv[q*4+1]=gv.y;  bgv[q*4+2]=gv.z;  bgv[q*4+3]=gv.w;
        bov[q*4+0]=ov.x;  bov[q*4+1]=ov.y;  bov[q*4+2]=ov.z;  bov[q*4+3]=ov.w;
    }

    // stage m_norm tile
    for (int idx = tid; idx < 2048; idx += 256) {
        int r = idx >> 4, c4 = idx & 15;
        int s = s0 + r;
        float4 x4 = *(const float4*)&m[((size_t)s * IDIM + i) * 64 + c4 * 4];
        float4 g4 = *(const float4*)&gamma[c4 * 4];
        float4 b4 = *(const float4*)&beta[c4 * 4];
        float2 st = *(const float2*)&stats[((size_t)i * SDIM + s) * 2];
        float4 mn;
        mn.x = (x4.x - st.x) * st.y * g4.x + b4.x;
        mn.y = (x4.y - st.x) * st.y * g4.y + b4.y;
        mn.z = (x4.z - st.x) * st.y * g4.z + b4.z;
        mn.w = (x4.w - st.x) * st.y * g4.w + b4.w;
        *(float4*)&mnT[r * 68 + c4 * 4] = mn;
    }
    __syncthreads();

    float z0[16], z1[16];
    #pragma unroll
    for (int jj = 0; jj < 16; ++jj) { z0[jj] = 0.f; z1[jj] = 0.f; }
    const float* aP0 = &mnT[l * 68];
    const float* aP1 = &mnT[(l + 64) * 68];

    // GEMM1: z = mn @ Wg^T  (b from scalar loads of WgS[c][j])
    {
        const float* Bg = ws + WS_WGT + wv16;
        #pragma unroll 4
        for (int c4 = 0; c4 < 16; ++c4) {
            float4 a0 = *(const float4*)(aP0 + c4 * 4);
            float4 a1 = *(const float4*)(aP1 + c4 * 4);
            float a0a[4] = {a0.x, a0.y, a0.z, a0.w};
            float a1a[4] = {a1.x, a1.y, a1.z, a1.w};
            #pragma unroll
            for (int cc = 0; cc < 4; ++cc) {
                f16v bv = *(const f16v*)(Bg + (c4 * 4 + cc) * 64);
                float av0 = a0a[cc], av1 = a1a[cc];
                #pragma unroll
                for (int jj = 0; jj < 16; ++jj) {
                    z0[jj] += av0 * bv[jj];
                    z1[jj] += av1 * bv[jj];
                }
            }
        }
    }
    __syncthreads();   // all GEMM1 LDS reads done before overwriting with o

    // gate: o = ctx * sigmoid(z + bg) -> back into mnT (own 16-col slab)
    #pragma unroll
    for (int jj = 0; jj < 16; ++jj) {
        z0[jj] = ctxv[jj] / (1.f + expf(-(z0[jj] + bgv[jj])));
        z1[jj] = ctxv[jj] / (1.f + expf(-(z1[jj] + bgv[jj])));
    }
    #pragma unroll
    for (int q = 0; q < 4; ++q) {
        float4 t0 = {z0[q*4+0], z0[q*4+1], z0[q*4+2], z0[q*4+3]};
        float4 t1 = {z1[q*4+0], z1[q*4+1], z1[q*4+2], z1[q*4+3]};
        *(float4*)&mnT[l * 68 + wv16 + q * 4]        = t0;
        *(float4*)&mnT[(l + 64) * 68 + wv16 + q * 4] = t1;
    }
    #pragma unroll
    for (int jj = 0; jj < 16; ++jj) { z0[jj] = 0.f; z1[jj] = 0.f; }
    __syncthreads();

    // GEMM2: w = o @ Wo^T  (b from scalar loads of WoS[j][cc])
    {
        const float* Bo = ws + WS_WOT + wv16;
        #pragma unroll 4
        for (int c4 = 0; c4 < 16; ++c4) {
            float4 a0 = *(const float4*)(aP0 + c4 * 4);
            float4 a1 = *(const float4*)(aP1 + c4 * 4);
            float a0a[4] = {a0.x, a0.y, a0.z, a0.w};
            float a1a[4] = {a1.x, a1.y, a1.z, a1.w};
            #pragma unroll
            for (int cc = 0; cc < 4; ++cc) {
                f16v bv = *(const f16v*)(Bo + (c4 * 4 + cc) * 64);
                float av0 = a0a[cc], av1 = a1a[cc];
                #pragma unroll
                for (int jj = 0; jj < 16; ++jj) {
                    z0[jj] += av0 * bv[jj];
                    z1[jj] += av1 * bv[jj];
                }
            }
        }
    }
    __syncthreads();   // all GEMM2 LDS reads done before overwriting with out

    // + bo, park result in mnT for coalesced store
    #pragma unroll
    for (int q = 0; q < 4; ++q) {
        float4 t0 = {z0[q*4+0]+bov[q*4+0], z0[q*4+1]+bov[q*4+1],
                     z0[q*4+2]+bov[q*4+2], z0[q*4+3]+bov[q*4+3]};
        float4 t1 = {z1[q*4+0]+bov[q*4+0], z1[q*4+1]+bov[q*4+1],
                     z1[q*4+2]+bov[q*4+2], z1[q*4+3]+bov[q*4+3]};
        *(float4*)&mnT[l * 68 + wv16 + q * 4]        = t0;
        *(float4*)&mnT[(l + 64) * 68 + wv16 + q * 4] = t1;
    }
    __syncthreads();

    // coalesced store: 16 lanes cover one row's 256B
    for (int idx = tid; idx < 2048; idx += 256) {
        int r = idx >> 4, c4 = idx & 15;
        float4 v = *(const float4*)&mnT[r * 68 + c4 * 4];
        *(float4*)&out[((size_t)(s0 + r) * IDIM + i) * 64 + c4 * 4] = v;
    }
}

extern "C" void kernel_launch(void* const* d_in, const int* in_sizes, int n_in,
                              void* d_out, int out_size, void* d_ws, size_t ws_size,
                              hipStream_t stream) {
    const float* m    = (const float*)d_in[0];
    const float* mask = (const float*)d_in[1];
    const float* gam  = (const float*)d_in[2];
    const float* bet  = (const float*)d_in[3];
    const float* Wq   = (const float*)d_in[4];
    const float* Wk   = (const float*)d_in[5];
    const float* Wv   = (const float*)d_in[6];
    const float* Wg   = (const float*)d_in[7];
    const float* bg   = (const float*)d_in[8];
    const float* Wo   = (const float*)d_in[9];
    const float* bo   = (const float*)d_in[10];
    float* out = (float*)d_out;
    float* ws  = (float*)d_ws;
    (void)in_sizes; (void)n_in; (void)out_size; (void)ws_size;

    kW<<<64, 64, 0, stream>>>(Wg, Wo, ws);
    kA<<<IDIM * NCH, 256, 0, stream>>>(m, mask, gam, bet, ws);
    kB<<<IDIM, 64, 0, stream>>>(Wq, ws);
    kC<<<IDIM * NCH, 256, 0, stream>>>(m, mask, gam, bet, Wk, Wv, ws);
    kD<<<IDIM, 64, 0, stream>>>(ws);
    kE<<<IDIM * (SDIM / 128), 256, 0, stream>>>(m, gam, bet, bg, bo, ws, out);
}

// Round 2
// 602.770 us; speedup vs baseline: 1.0214x; 1.0214x over previous
//
#include <hip/hip_runtime.h>

#define IDIM 384
#define SDIM 2048
#define NCH  8
#define CHUNK 256

// workspace layout (float offsets)
#define WS_STATS 0                                  // [I][S][2]  (mu, rstd)
#define WS_QGP   (IDIM*SDIM*2)                      // [I][NCH][65] (qg partial + count)
#define WS_Q     (WS_QGP + IDIM*NCH*65)             // [I][64]   scaled q
#define WS_ATT   (WS_Q + IDIM*64)                   // [I][NCH][8][10] (m,l,ctx[8])
#define WS_CTX   (WS_ATT + IDIM*NCH*8*10)           // [I][64]
#define WS_WGT   (WS_CTX + IDIM*64)                 // [64][64]  WgS[c][j] = Wg[j][c]
#define WS_WOT   (WS_WGT + 64*64)                   // [64][64]  WoS[j][cc] = Wo[cc][j]
#define WS_KV    (WS_WOT + 64*64)                   // [I][S][16] (k[8], v[8]) -- fused path only

typedef float f16v __attribute__((ext_vector_type(16)));

// ---------------- Kernel A: LN stats + q_global partials (+ optional k/v) --
// 8 lanes per row; 3 shuffles for the LN reduce. DOKV: compute k/v rows from
// in-register m_norm via LDS-staged weights + 8-lane butterfly, store to ws.
template<bool DOKV>
__global__ __launch_bounds__(256) void kA2(const float* __restrict__ m,
                                           const float* __restrict__ mask,
                                           const float* __restrict__ gamma,
                                           const float* __restrict__ beta,
                                           const float* __restrict__ Wk,
                                           const float* __restrict__ Wv,
                                           float* __restrict__ ws) {
    int bx = blockIdx.x;
    int i = bx >> 3, chk = bx & 7;
    int tid = threadIdx.x;
    int rg = tid >> 3;      // 0..31 row-group within 32-row tile
    int c8 = tid & 7;       // which 8-element channel slice
    __shared__ float Wk_s[8 * 68], Wv_s[8 * 68];
    if (DOKV) {
        for (int idx = tid; idx < 512; idx += 256) {
            int r = idx >> 6, c = idx & 63;
            Wk_s[r * 68 + c] = Wk[idx];
            Wv_s[r * 68 + c] = Wv[idx];
        }
        __syncthreads();
    }
    float4 ga4 = *(const float4*)&gamma[c8 * 8];
    float4 gb4 = *(const float4*)&gamma[c8 * 8 + 4];
    float4 ba4 = *(const float4*)&beta[c8 * 8];
    float4 bb4 = *(const float4*)&beta[c8 * 8 + 4];
    float g[8] = {ga4.x, ga4.y, ga4.z, ga4.w, gb4.x, gb4.y, gb4.z, gb4.w};
    float b[8] = {ba4.x, ba4.y, ba4.z, ba4.w, bb4.x, bb4.y, bb4.z, bb4.w};
    float qg[8];
    #pragma unroll
    for (int j = 0; j < 8; ++j) qg[j] = 0.f;
    float cnt = 0.f;
    float* stats = ws + WS_STATS;

    for (int t = 0; t < 8; ++t) {
        int s = chk * CHUNK + t * 32 + rg;
        const float* mp = &m[((size_t)s * IDIM + i) * 64 + c8 * 8];
        float4 xa = *(const float4*)mp;
        float4 xb = *(const float4*)(mp + 4);
        float x[8] = {xa.x, xa.y, xa.z, xa.w, xb.x, xb.y, xb.z, xb.w};
        float sx = 0.f, sxx = 0.f;
        #pragma unroll
        for (int j = 0; j < 8; ++j) { sx += x[j]; sxx += x[j] * x[j]; }
        sx += __shfl_xor(sx, 1); sxx += __shfl_xor(sxx, 1);
        sx += __shfl_xor(sx, 2); sxx += __shfl_xor(sxx, 2);
        sx += __shfl_xor(sx, 4); sxx += __shfl_xor(sxx, 4);
        float mu  = sx * (1.f / 64.f);
        float var = sxx * (1.f / 64.f) - mu * mu;
        float rs  = rsqrtf(var + 1e-5f);
        float mk  = mask[s * IDIM + i];
        float mnv[8];
        #pragma unroll
        for (int j = 0; j < 8; ++j) {
            mnv[j] = (x[j] - mu) * rs * g[j] + b[j];
            qg[j] += mk * mnv[j];
        }
        if (c8 == 0) {
            cnt += mk;
            float2 st = {mu, rs};
            *(float2*)&stats[((size_t)i * SDIM + s) * 2] = st;
        }
        if (DOKV) {
            float kp[8], vp[8];
            #pragma unroll
            for (int h = 0; h < 8; ++h) {
                float4 wk0 = *(const float4*)&Wk_s[h * 68 + c8 * 8];
                float4 wk1 = *(const float4*)&Wk_s[h * 68 + c8 * 8 + 4];
                float4 wv0 = *(const float4*)&Wv_s[h * 68 + c8 * 8];
                float4 wv1 = *(const float4*)&Wv_s[h * 68 + c8 * 8 + 4];
                kp[h] = mnv[0]*wk0.x + mnv[1]*wk0.y + mnv[2]*wk0.z + mnv[3]*wk0.w
                      + mnv[4]*wk1.x + mnv[5]*wk1.y + mnv[6]*wk1.z + mnv[7]*wk1.w;
                vp[h] = mnv[0]*wv0.x + mnv[1]*wv0.y + mnv[2]*wv0.z + mnv[3]*wv0.w
                      + mnv[4]*wv1.x + mnv[5]*wv1.y + mnv[6]*wv1.z + mnv[7]*wv1.w;
            }
            #pragma unroll
            for (int h = 0; h < 8; ++h) {
                kp[h] += __shfl_xor(kp[h], 1); vp[h] += __shfl_xor(vp[h], 1);
                kp[h] += __shfl_xor(kp[h], 2); vp[h] += __shfl_xor(vp[h], 2);
                kp[h] += __shfl_xor(kp[h], 4); vp[h] += __shfl_xor(vp[h], 4);
            }
            float* kvp = ws + WS_KV + ((size_t)i * SDIM + s) * 16;
            // compile-time value index, predicated lane (avoids scratch)
            #pragma unroll
            for (int j = 0; j < 8; ++j) {
                if (c8 == j) { kvp[j] = kp[j]; kvp[8 + j] = vp[j]; }
            }
        }
    }
    __shared__ float red[32][68];
    #pragma unroll
    for (int j = 0; j < 8; ++j) red[rg][c8 * 8 + j] = qg[j];
    if (c8 == 0) red[rg][64] = cnt;
    __syncthreads();
    if (tid < 65) {
        float v = 0.f;
        #pragma unroll
        for (int r = 0; r < 32; ++r) v += red[r][tid];
        ws[WS_QGP + (i * NCH + chk) * 65 + tid] = v;
    }
}

// ---------------- Kernel B: reduce q_global, q = (qg @ WqT)/sqrt(8); + W^T --
__global__ __launch_bounds__(64) void kB(const float* __restrict__ Wq,
                                         const float* __restrict__ Wg,
                                         const float* __restrict__ Wo,
                                         float* __restrict__ ws) {
    int i = blockIdx.x, l = threadIdx.x;
    if (i < 64) {   // fold in the weight transposes (was kernel kW)
        ws[WS_WGT + i * 64 + l] = Wg[l * 64 + i];
        ws[WS_WOT + i * 64 + l] = Wo[l * 64 + i];
    }
    float sum = 0.f, cnt = 0.f;
    #pragma unroll
    for (int c = 0; c < NCH; ++c) {
        sum += ws[WS_QGP + (i * NCH + c) * 65 + l];
        cnt += ws[WS_QGP + (i * NCH + c) * 65 + 64];
    }
    float denom = fmaxf(cnt, 1e-5f);
    __shared__ float qg[64];
    qg[l] = sum / denom;
    __syncthreads();
    float acc = 0.f;
    #pragma unroll 8
    for (int c = 0; c < 64; ++c) acc += qg[c] * Wq[l * 64 + c];
    ws[WS_Q + i * 64 + l] = acc * 0.35355339059327373f;  // fold in 1/sqrt(CH)
}

// ---------------- Kernel C2 (fused path): attention from precomputed k/v ---
__global__ __launch_bounds__(256) void kC2(const float* __restrict__ mask,
                                           float* __restrict__ ws) {
    int bx = blockIdx.x;
    int i = bx >> 3, chk = bx & 7;
    int tid = threadIdx.x;
    __shared__ float kv_s[256 * 20];
    __shared__ float red[32 * 8 * 10];

    // stage this chunk's k/v: 256 rows x 16 floats, contiguous in ws
    const float* kvg = ws + WS_KV + ((size_t)i * SDIM + chk * CHUNK) * 16;
    for (int idx = tid; idx < 1024; idx += 256) {
        int r = idx >> 2, c4 = idx & 3;
        *(float4*)&kv_s[r * 20 + c4 * 4] = *(const float4*)&kvg[idx * 4];
    }
    int sr = tid >> 3;   // 0..31
    int lo = tid & 7;    // head
    const float* wq = ws + WS_Q + i * 64 + lo * 8;
    float4 q0 = *(const float4*)wq;
    float4 q1 = *(const float4*)(wq + 4);
    float m_run = -1e30f, l_run = 0.f, ctx[8];
    #pragma unroll
    for (int z = 0; z < 8; ++z) ctx[z] = 0.f;
    __syncthreads();

    for (int t = 0; t < 8; ++t) {
        int r = t * 32 + sr;
        float4 k0 = *(const float4*)&kv_s[r * 20];
        float4 k1 = *(const float4*)&kv_s[r * 20 + 4];
        float4 v0 = *(const float4*)&kv_s[r * 20 + 8];
        float4 v1 = *(const float4*)&kv_s[r * 20 + 12];
        float lg = q0.x*k0.x + q0.y*k0.y + q0.z*k0.z + q0.w*k0.w
                 + q1.x*k1.x + q1.y*k1.y + q1.z*k1.z + q1.w*k1.w;
        float mk = mask[(chk * CHUNK + r) * IDIM + i];
        lg = (mk > 0.f) ? lg : -1e9f;
        float mnew = fmaxf(m_run, lg);
        float al = expf(m_run - mnew);
        float p  = expf(lg - mnew);
        l_run = l_run * al + p;
        ctx[0] = ctx[0]*al + p*v0.x; ctx[1] = ctx[1]*al + p*v0.y;
        ctx[2] = ctx[2]*al + p*v0.z; ctx[3] = ctx[3]*al + p*v0.w;
        ctx[4] = ctx[4]*al + p*v1.x; ctx[5] = ctx[5]*al + p*v1.y;
        ctx[6] = ctx[6]*al + p*v1.z; ctx[7] = ctx[7]*al + p*v1.w;
        m_run = mnew;
    }
    int base = (sr * 8 + lo) * 10;
    red[base] = m_run; red[base + 1] = l_run;
    #pragma unroll
    for (int c = 0; c < 8; ++c) red[base + 2 + c] = ctx[c];
    __syncthreads();
    if (tid < 64) {
        int h = tid >> 3, c2 = tid & 7;
        float M = -1e30f;
        for (int r = 0; r < 32; ++r) M = fmaxf(M, red[(r * 8 + h) * 10]);
        float L = 0.f, CT = 0.f;
        for (int r = 0; r < 32; ++r) {
            float e = expf(red[(r * 8 + h) * 10] - M);
            L += red[(r * 8 + h) * 10 + 1] * e;
            CT += red[(r * 8 + h) * 10 + 2 + c2] * e;
        }
        float* dst = ws + WS_ATT + ((i * NCH + chk) * 8 + h) * 10;
        if (c2 == 0) { dst[0] = M; dst[1] = L; }
        dst[2 + c2] = CT;
    }
}

// ---------------- Kernel C (fallback): k/v + flash partials, reads m -------
__global__ __launch_bounds__(256) void kC(const float* __restrict__ m,
                                          const float* __restrict__ mask,
                                          const float* __restrict__ gamma,
                                          const float* __restrict__ beta,
                                          const float* __restrict__ Wk,
                                          const float* __restrict__ Wv,
                                          float* __restrict__ ws) {
    int bx = blockIdx.x;
    int i = bx >> 3, chk = bx & 7;
    int tid = threadIdx.x;
    __shared__ float mnT[32 * 68];
    __shared__ float Wk_s[8 * 68], Wv_s[8 * 68];
    __shared__ float k_s[32 * 9], v_s[32 * 9];
    __shared__ float q_s[64];
    __shared__ float red[32 * 8 * 10];
    const float* stats = ws + WS_STATS;

    if (tid < 64) q_s[tid] = ws[WS_Q + i * 64 + tid];
    for (int idx = tid; idx < 512; idx += 256) {
        int r = idx >> 6, c = idx & 63;
        Wk_s[r * 68 + c] = Wk[idx];
        Wv_s[r * 68 + c] = Wv[idx];
    }
    int sr = tid >> 3;
    int lo = tid & 7;
    float m_run = -1e30f, l_run = 0.f, ctx[8];
    #pragma unroll
    for (int z = 0; z < 8; ++z) ctx[z] = 0.f;
    __syncthreads();

    for (int t = 0; t < 8; ++t) {
        int sbase = chk * CHUNK + t * 32;
        for (int idx = tid; idx < 512; idx += 256) {
            int r = idx >> 4, c4 = idx & 15;
            int s = sbase + r;
            float4 x4 = *(const float4*)&m[((size_t)s * IDIM + i) * 64 + c4 * 4];
            float4 g4 = *(const float4*)&gamma[c4 * 4];
            float4 b4 = *(const float4*)&beta[c4 * 4];
            float2 st = *(const float2*)&stats[((size_t)i * SDIM + s) * 2];
            float4 mn;
            mn.x = (x4.x - st.x) * st.y * g4.x + b4.x;
            mn.y = (x4.y - st.x) * st.y * g4.y + b4.y;
            mn.z = (x4.z - st.x) * st.y * g4.z + b4.z;
            mn.w = (x4.w - st.x) * st.y * g4.w + b4.w;
            *(float4*)&mnT[r * 68 + c4 * 4] = mn;
        }
        __syncthreads();
        {
            float accK = 0.f, accV = 0.f;
            #pragma unroll
            for (int c4 = 0; c4 < 16; ++c4) {
                float4 a  = *(const float4*)&mnT[sr * 68 + c4 * 4];
                float4 wk = *(const float4*)&Wk_s[lo * 68 + c4 * 4];
                float4 wv = *(const float4*)&Wv_s[lo * 68 + c4 * 4];
                accK += a.x * wk.x + a.y * wk.y + a.z * wk.z + a.w * wk.w;
                accV += a.x * wv.x + a.y * wv.y + a.z * wv.z + a.w * wv.w;
            }
            k_s[sr * 9 + lo] = accK;
            v_s[sr * 9 + lo] = accV;
        }
        __syncthreads();
        {
            float lg = 0.f;
            #pragma unroll
            for (int c = 0; c < 8; ++c) lg += q_s[lo * 8 + c] * k_s[sr * 9 + c];
            float mk = mask[(sbase + sr) * IDIM + i];
            lg = (mk > 0.f) ? lg : -1e9f;
            float mnew = fmaxf(m_run, lg);
            float al = expf(m_run - mnew);
            float p  = expf(lg - mnew);
            l_run = l_run * al + p;
            #pragma unroll
            for (int c = 0; c < 8; ++c) ctx[c] = ctx[c] * al + p * v_s[sr * 9 + c];
            m_run = mnew;
        }
        __syncthreads();
    }
    int base = (sr * 8 + lo) * 10;
    red[base] = m_run; red[base + 1] = l_run;
    #pragma unroll
    for (int c = 0; c < 8; ++c) red[base + 2 + c] = ctx[c];
    __syncthreads();
    if (tid < 64) {
        int h = tid >> 3, c2 = tid & 7;
        float M = -1e30f;
        for (int r = 0; r < 32; ++r) M = fmaxf(M, red[(r * 8 + h) * 10]);
        float L = 0.f, CT = 0.f;
        for (int r = 0; r < 32; ++r) {
            float e = expf(red[(r * 8 + h) * 10] - M);
            L += red[(r * 8 + h) * 10 + 1] * e;
            CT += red[(r * 8 + h) * 10 + 2 + c2] * e;
        }
        float* dst = ws + WS_ATT + ((i * NCH + chk) * 8 + h) * 10;
        if (c2 == 0) { dst[0] = M; dst[1] = L; }
        dst[2 + c2] = CT;
    }
}

// ---------------- Kernel D: merge chunk partials -> ctx --------------------
__global__ __launch_bounds__(64) void kD(float* __restrict__ ws) {
    int i = blockIdx.x, l = threadIdx.x;
    int h = l >> 3, c2 = l & 7;
    float M = -1e30f;
    #pragma unroll
    for (int c = 0; c < NCH; ++c)
        M = fmaxf(M, ws[WS_ATT + ((i * NCH + c) * 8 + h) * 10]);
    float L = 0.f, CT = 0.f;
    #pragma unroll
    for (int c = 0; c < NCH; ++c) {
        const float* src = ws + WS_ATT + ((i * NCH + c) * 8 + h) * 10;
        float e = expf(src[0] - M);
        L += src[1] * e;
        CT += src[2 + c2] * e;
    }
    ws[WS_CTX + i * 64 + l] = CT / L;
}

// ---------------- Kernel E: g = sigmoid(mn@WgT+bg); out=(ctx*g)@WoT+bo -----
// 64-row tiles (LDS 17.4KB) + __launch_bounds__(256,8) -> 8 blocks/CU,
// 32 waves/CU. b-operand stays scalar (s_load of pre-transposed slabs).
__global__ __launch_bounds__(256, 8) void kE(const float* __restrict__ m,
                                             const float* __restrict__ gamma,
                                             const float* __restrict__ beta,
                                             const float* __restrict__ bg,
                                             const float* __restrict__ bo,
                                             const float* __restrict__ ws,
                                             float* __restrict__ out) {
    int bx = blockIdx.x;
    int i = bx >> 5;        // 32 tiles of 64 rows per column
    int tile = bx & 31;
    int tid = threadIdx.x;
    int l = tid & 63;
    int wv16 = __builtin_amdgcn_readfirstlane((tid >> 6) << 4);  // wave's col base
    __shared__ float mnT[64 * 68];
    const float* stats = ws + WS_STATS;
    int s0 = tile * 64;

    float ctxv[16], bgv[16], bov[16];
    #pragma unroll
    for (int q = 0; q < 4; ++q) {
        float4 cv = *(const float4*)&ws[WS_CTX + i * 64 + wv16 + q * 4];
        float4 gv = *(const float4*)&bg[wv16 + q * 4];
        float4 ov = *(const float4*)&bo[wv16 + q * 4];
        ctxv[q*4+0]=cv.x; ctxv[q*4+1]=cv.y; ctxv[q*4+2]=cv.z; ctxv[q*4+3]=cv.w;
        bgv[q*4+0]=gv.x;  bgv[q*4+1]=gv.y;  bgv[q*4+2]=gv.z;  bgv[q*4+3]=gv.w;
        bov[q*4+0]=ov.x;  bov[q*4+1]=ov.y;  bov[q*4+2]=ov.z;  bov[q*4+3]=ov.w;
    }

    // stage m_norm tile (64 rows)
    for (int idx = tid; idx < 1024; idx += 256) {
        int r = idx >> 4, c4 = idx & 15;
        int s = s0 + r;
        float4 x4 = *(const float4*)&m[((size_t)s * IDIM + i) * 64 + c4 * 4];
        float4 g4 = *(const float4*)&gamma[c4 * 4];
        float4 b4 = *(const float4*)&beta[c4 * 4];
        float2 st = *(const float2*)&stats[((size_t)i * SDIM + s) * 2];
        float4 mn;
        mn.x = (x4.x - st.x) * st.y * g4.x + b4.x;
        mn.y = (x4.y - st.x) * st.y * g4.y + b4.y;
        mn.z = (x4.z - st.x) * st.y * g4.z + b4.z;
        mn.w = (x4.w - st.x) * st.y * g4.w + b4.w;
        *(float4*)&mnT[r * 68 + c4 * 4] = mn;
    }
    __syncthreads();

    float z[16];
    #pragma unroll
    for (int jj = 0; jj < 16; ++jj) z[jj] = 0.f;
    const float* aP = &mnT[l * 68];

    // GEMM1: z = mn @ Wg^T  (b from scalar loads of WgS[c][j])
    {
        const float* Bg = ws + WS_WGT + wv16;
        #pragma unroll 4
        for (int c4 = 0; c4 < 16; ++c4) {
            float4 a0 = *(const float4*)(aP + c4 * 4);
            float aa[4] = {a0.x, a0.y, a0.z, a0.w};
            #pragma unroll
            for (int cc = 0; cc < 4; ++cc) {
                f16v bv = *(const f16v*)(Bg + (c4 * 4 + cc) * 64);
                float av = aa[cc];
                #pragma unroll
                for (int jj = 0; jj < 16; ++jj) z[jj] += av * bv[jj];
            }
        }
    }
    __syncthreads();   // GEMM1 LDS reads done before overwriting with o

    // gate: o = ctx * sigmoid(z + bg) -> park in own 16-col slab
    #pragma unroll
    for (int jj = 0; jj < 16; ++jj)
        z[jj] = ctxv[jj] / (1.f + expf(-(z[jj] + bgv[jj])));
    #pragma unroll
    for (int q = 0; q < 4; ++q) {
        float4 t0 = {z[q*4+0], z[q*4+1], z[q*4+2], z[q*4+3]};
        *(float4*)&mnT[l * 68 + wv16 + q * 4] = t0;
    }
    #pragma unroll
    for (int jj = 0; jj < 16; ++jj) z[jj] = 0.f;
    __syncthreads();

    // GEMM2: w = o @ Wo^T  (b from scalar loads of WoS[j][cc])
    {
        const float* Bo = ws + WS_WOT + wv16;
        #pragma unroll 4
        for (int c4 = 0; c4 < 16; ++c4) {
            float4 a0 = *(const float4*)(aP + c4 * 4);
            float aa[4] = {a0.x, a0.y, a0.z, a0.w};
            #pragma unroll
            for (int cc = 0; cc < 4; ++cc) {
                f16v bv = *(const f16v*)(Bo + (c4 * 4 + cc) * 64);
                float av = aa[cc];
                #pragma unroll
                for (int jj = 0; jj < 16; ++jj) z[jj] += av * bv[jj];
            }
        }
    }
    __syncthreads();   // GEMM2 LDS reads done before overwriting with out

    #pragma unroll
    for (int q = 0; q < 4; ++q) {
        float4 t0 = {z[q*4+0]+bov[q*4+0], z[q*4+1]+bov[q*4+1],
                     z[q*4+2]+bov[q*4+2], z[q*4+3]+bov[q*4+3]};
        *(float4*)&mnT[l * 68 + wv16 + q * 4] = t0;
    }
    __syncthreads();

    // coalesced store: 16 lanes cover one row's 256B
    for (int idx = tid; idx < 1024; idx += 256) {
        int r = idx >> 4, c4 = idx & 15;
        float4 v = *(const float4*)&mnT[r * 68 + c4 * 4];
        *(float4*)&out[((size_t)(s0 + r) * IDIM + i) * 64 + c4 * 4] = v;
    }
}

extern "C" void kernel_launch(void* const* d_in, const int* in_sizes, int n_in,
                              void* d_out, int out_size, void* d_ws, size_t ws_size,
                              hipStream_t stream) {
    const float* m    = (const float*)d_in[0];
    const float* mask = (const float*)d_in[1];
    const float* gam  = (const float*)d_in[2];
    const float* bet  = (const float*)d_in[3];
    const float* Wq   = (const float*)d_in[4];
    const float* Wk   = (const float*)d_in[5];
    const float* Wv   = (const float*)d_in[6];
    const float* Wg   = (const float*)d_in[7];
    const float* bg   = (const float*)d_in[8];
    const float* Wo   = (const float*)d_in[9];
    const float* bo   = (const float*)d_in[10];
    float* out = (float*)d_out;
    float* ws  = (float*)d_ws;
    (void)in_sizes; (void)n_in; (void)out_size;

    size_t need_fused = (size_t)(WS_KV + (size_t)IDIM * SDIM * 16) * sizeof(float);
    bool fused = ws_size >= need_fused;

    if (fused)
        kA2<true><<<IDIM * NCH, 256, 0, stream>>>(m, mask, gam, bet, Wk, Wv, ws);
    else
        kA2<false><<<IDIM * NCH, 256, 0, stream>>>(m, mask, gam, bet, Wk, Wv, ws);
    kB<<<IDIM, 64, 0, stream>>>(Wq, Wg, Wo, ws);
    if (fused)
        kC2<<<IDIM * NCH, 256, 0, stream>>>(mask, ws);
    else
        kC<<<IDIM * NCH, 256, 0, stream>>>(m, mask, gam, bet, Wk, Wv, ws);
    kD<<<IDIM, 64, 0, stream>>>(ws);
    kE<<<IDIM * (SDIM / 64), 256, 0, stream>>>(m, gam, bet, bg, bo, ws, out);
}

// Round 3
// 556.765 us; speedup vs baseline: 1.1058x; 1.0826x over previous
//
#include <hip/hip_runtime.h>

#define IDIM 384
#define SDIM 2048
#define NCH  8
#define CHUNK 256

// workspace layout (float offsets)
#define WS_STATS 0                                  // [I][S][2]  (mu, rstd)
#define WS_QGP   (IDIM*SDIM*2)                      // [I][NCH][65] (qg partial + count)
#define WS_Q     (WS_QGP + IDIM*NCH*65)             // [I][64]   scaled q (fallback path)
#define WS_ATT   (WS_Q + IDIM*64)                   // [I][NCH][8][10] (m,l,ctx[8])
#define WS_CTX   (WS_ATT + IDIM*NCH*8*10)           // [I][64] (unused now, kept for layout)
#define WS_WGT   (WS_CTX + IDIM*64)                 // [64][64]  WgS[c][j] = Wg[j][c]
#define WS_WOT   (WS_WGT + 64*64)                   // [64][64]  WoS[j][cc] = Wo[cc][j]
#define WS_KV    (WS_WOT + 64*64)                   // [I][S][16] (k[8], v[8]) -- fused path

typedef float sf16 __attribute__((ext_vector_type(16)));

// ---------------- Kernel A: LN stats + q_global partials (+ k/v fused) -----
// 8 lanes per row. Wk/Wv slices hoisted to registers (loaded once), k/v
// cross-lane reduce via 14-shuffle select-tree (compile-time reg indices).
// Grid is chunk-major: consecutive blocks read adjacent 256B m segments.
template<bool DOKV>
__global__ __launch_bounds__(256) void kA2(const float* __restrict__ m,
                                           const float* __restrict__ mask,
                                           const float* __restrict__ gamma,
                                           const float* __restrict__ beta,
                                           const float* __restrict__ Wk,
                                           const float* __restrict__ Wv,
                                           const float* __restrict__ Wg,
                                           const float* __restrict__ Wo,
                                           float* __restrict__ ws) {
    int bx = blockIdx.x;
    int chk = bx / IDIM;
    int i = bx - chk * IDIM;
    int tid = threadIdx.x;
    int rg = tid >> 3;      // 0..31 row within 32-row tile
    int c8 = tid & 7;       // 8-element channel slice

    // fold: weight transposes for kE (16 blocks x 256 threads cover 4096)
    if (bx < 16) {
        int g = bx * 256 + tid;
        int r = g >> 6, c = g & 63;
        ws[WS_WGT + g] = Wg[c * 64 + r];
        ws[WS_WOT + g] = Wo[c * 64 + r];
    }

    float4 ga4 = *(const float4*)&gamma[c8 * 8];
    float4 gb4 = *(const float4*)&gamma[c8 * 8 + 4];
    float4 ba4 = *(const float4*)&beta[c8 * 8];
    float4 bb4 = *(const float4*)&beta[c8 * 8 + 4];
    float g[8] = {ga4.x, ga4.y, ga4.z, ga4.w, gb4.x, gb4.y, gb4.z, gb4.w};
    float b[8] = {ba4.x, ba4.y, ba4.z, ba4.w, bb4.x, bb4.y, bb4.z, bb4.w};

    float4 wkr[16], wvr[16];    // Wk/Wv [h][c8-slice], hoisted (DOKV only)
    if (DOKV) {
        #pragma unroll
        for (int h = 0; h < 8; ++h) {
            wkr[h * 2]     = *(const float4*)&Wk[h * 64 + c8 * 8];
            wkr[h * 2 + 1] = *(const float4*)&Wk[h * 64 + c8 * 8 + 4];
            wvr[h * 2]     = *(const float4*)&Wv[h * 64 + c8 * 8];
            wvr[h * 2 + 1] = *(const float4*)&Wv[h * 64 + c8 * 8 + 4];
        }
    }

    float qg[8];
    #pragma unroll
    for (int j = 0; j < 8; ++j) qg[j] = 0.f;
    float cnt = 0.f;
    float* stats = ws + WS_STATS;

    // prefetch t=0
    int s0 = chk * CHUNK + rg;
    float4 xa = *(const float4*)&m[((size_t)s0 * IDIM + i) * 64 + c8 * 8];
    float4 xb = *(const float4*)&m[((size_t)s0 * IDIM + i) * 64 + c8 * 8 + 4];

    for (int t = 0; t < 8; ++t) {
        int s = chk * CHUNK + t * 32 + rg;
        float x[8] = {xa.x, xa.y, xa.z, xa.w, xb.x, xb.y, xb.z, xb.w};
        if (t < 7) {    // prefetch next tile
            int sn = s + 32;
            xa = *(const float4*)&m[((size_t)sn * IDIM + i) * 64 + c8 * 8];
            xb = *(const float4*)&m[((size_t)sn * IDIM + i) * 64 + c8 * 8 + 4];
        }
        float sx = 0.f, sxx = 0.f;
        #pragma unroll
        for (int j = 0; j < 8; ++j) { sx += x[j]; sxx += x[j] * x[j]; }
        sx += __shfl_xor(sx, 1); sxx += __shfl_xor(sxx, 1);
        sx += __shfl_xor(sx, 2); sxx += __shfl_xor(sxx, 2);
        sx += __shfl_xor(sx, 4); sxx += __shfl_xor(sxx, 4);
        float mu  = sx * (1.f / 64.f);
        float var = sxx * (1.f / 64.f) - mu * mu;
        float rs  = rsqrtf(var + 1e-5f);
        float mk  = mask[s * IDIM + i];
        float mnv[8];
        #pragma unroll
        for (int j = 0; j < 8; ++j) {
            mnv[j] = (x[j] - mu) * rs * g[j] + b[j];
            qg[j] += mk * mnv[j];
        }
        if (c8 == 0) {
            cnt += mk;
            float2 st = {mu, rs};
            *(float2*)&stats[((size_t)i * SDIM + s) * 2] = st;
        }
        if (DOKV) {
            float kp[8], vp[8];
            #pragma unroll
            for (int h = 0; h < 8; ++h) {
                float4 a0 = wkr[h * 2], a1 = wkr[h * 2 + 1];
                kp[h] = mnv[0]*a0.x + mnv[1]*a0.y + mnv[2]*a0.z + mnv[3]*a0.w
                      + mnv[4]*a1.x + mnv[5]*a1.y + mnv[6]*a1.z + mnv[7]*a1.w;
                float4 c0 = wvr[h * 2], c1 = wvr[h * 2 + 1];
                vp[h] = mnv[0]*c0.x + mnv[1]*c0.y + mnv[2]*c0.z + mnv[3]*c0.w
                      + mnv[4]*c1.x + mnv[5]*c1.y + mnv[6]*c1.z + mnv[7]*c1.w;
            }
            // select-tree reduce across the 8 lanes of this row:
            // final: lane c8 holds full dot for head h=c8. All reg indices
            // compile-time (rule: no runtime-indexed arrays -> no scratch).
            bool s4 = (c8 & 4) != 0, s2 = (c8 & 2) != 0, s1 = (c8 & 1) != 0;
            float k4[4], v4[4];
            #pragma unroll
            for (int hh = 0; hh < 4; ++hh) {
                float ka = s4 ? kp[hh + 4] : kp[hh];
                float kb = s4 ? kp[hh] : kp[hh + 4];
                k4[hh] = ka + __shfl_xor(kb, 4);
                float va = s4 ? vp[hh + 4] : vp[hh];
                float vb = s4 ? vp[hh] : vp[hh + 4];
                v4[hh] = va + __shfl_xor(vb, 4);
            }
            float k2[2], v2[2];
            #pragma unroll
            for (int hh = 0; hh < 2; ++hh) {
                float ka = s2 ? k4[hh + 2] : k4[hh];
                float kb = s2 ? k4[hh] : k4[hh + 2];
                k2[hh] = ka + __shfl_xor(kb, 2);
                float va = s2 ? v4[hh + 2] : v4[hh];
                float vb = s2 ? v4[hh] : v4[hh + 2];
                v2[hh] = va + __shfl_xor(vb, 2);
            }
            float kf = (s1 ? k2[1] : k2[0]) + __shfl_xor(s1 ? k2[0] : k2[1], 1);
            float vf = (s1 ? v2[1] : v2[0]) + __shfl_xor(s1 ? v2[0] : v2[1], 1);
            float* kvp = ws + WS_KV + ((size_t)i * SDIM + s) * 16;
            kvp[c8]     = kf;
            kvp[8 + c8] = vf;
        }
    }
    __shared__ float red[32][68];
    #pragma unroll
    for (int j = 0; j < 8; ++j) red[rg][c8 * 8 + j] = qg[j];
    if (c8 == 0) red[rg][64] = cnt;
    __syncthreads();
    if (tid < 65) {
        float v = 0.f;
        #pragma unroll
        for (int r = 0; r < 32; ++r) v += red[r][tid];
        ws[WS_QGP + (i * NCH + chk) * 65 + tid] = v;
    }
}

// ---------------- Kernel B (fallback only): q = (qg @ WqT)/sqrt(8) ---------
__global__ __launch_bounds__(64) void kB(const float* __restrict__ Wq,
                                         float* __restrict__ ws) {
    int i = blockIdx.x, l = threadIdx.x;
    float sum = 0.f, cnt = 0.f;
    #pragma unroll
    for (int c = 0; c < NCH; ++c) {
        sum += ws[WS_QGP + (i * NCH + c) * 65 + l];
        cnt += ws[WS_QGP + (i * NCH + c) * 65 + 64];
    }
    float denom = fmaxf(cnt, 1e-5f);
    __shared__ float qg[64];
    qg[l] = sum / denom;
    __syncthreads();
    float acc = 0.f;
    #pragma unroll 8
    for (int c = 0; c < 64; ++c) acc += qg[c] * Wq[l * 64 + c];
    ws[WS_Q + i * 64 + l] = acc * 0.35355339059327373f;
}

// ---------------- Kernel C2 (fused): q-compute + attention from ws kv ------
__global__ __launch_bounds__(256) void kC2(const float* __restrict__ mask,
                                           const float* __restrict__ Wq,
                                           float* __restrict__ ws) {
    int bx = blockIdx.x;
    int chk = bx / IDIM;
    int i = bx - chk * IDIM;
    int tid = threadIdx.x;
    __shared__ float kv_s[256 * 20];
    __shared__ float red[32 * 8 * 10];
    __shared__ float qg_s[64];
    __shared__ float q_s[64];

    // stage this chunk's k/v (contiguous 16KB)
    const float* kvg = ws + WS_KV + ((size_t)i * SDIM + chk * CHUNK) * 16;
    for (int idx = tid; idx < 1024; idx += 256) {
        int r = idx >> 2, c4 = idx & 3;
        *(float4*)&kv_s[r * 20 + c4 * 4] = *(const float4*)&kvg[idx * 4];
    }
    // fold kB: compute q for this column (redundant per chunk, trivial)
    if (tid < 64) {
        float sum = 0.f, cnt = 0.f;
        #pragma unroll
        for (int c = 0; c < 8; ++c) {
            sum += ws[WS_QGP + (i * NCH + c) * 65 + tid];
            cnt += ws[WS_QGP + (i * NCH + c) * 65 + 64];
        }
        qg_s[tid] = sum / fmaxf(cnt, 1e-5f);
    }
    __syncthreads();
    if (tid < 64) {
        float acc = 0.f;
        #pragma unroll 8
        for (int c = 0; c < 64; ++c) acc += qg_s[c] * Wq[tid * 64 + c];
        q_s[tid] = acc * 0.35355339059327373f;
    }
    __syncthreads();

    int sr = tid >> 3;   // 0..31
    int lo = tid & 7;    // head
    float4 q0 = *(const float4*)&q_s[lo * 8];
    float4 q1 = *(const float4*)&q_s[lo * 8 + 4];
    float m_run = -1e30f, l_run = 0.f, ctx[8];
    #pragma unroll
    for (int z = 0; z < 8; ++z) ctx[z] = 0.f;

    for (int t = 0; t < 8; ++t) {
        int r = t * 32 + sr;
        float4 k0 = *(const float4*)&kv_s[r * 20];
        float4 k1 = *(const float4*)&kv_s[r * 20 + 4];
        float4 v0 = *(const float4*)&kv_s[r * 20 + 8];
        float4 v1 = *(const float4*)&kv_s[r * 20 + 12];
        float lg = q0.x*k0.x + q0.y*k0.y + q0.z*k0.z + q0.w*k0.w
                 + q1.x*k1.x + q1.y*k1.y + q1.z*k1.z + q1.w*k1.w;
        float mk = mask[(chk * CHUNK + r) * IDIM + i];
        lg = (mk > 0.f) ? lg : -1e9f;
        float mnew = fmaxf(m_run, lg);
        float al = expf(m_run - mnew);
        float p  = expf(lg - mnew);
        l_run = l_run * al + p;
        ctx[0] = ctx[0]*al + p*v0.x; ctx[1] = ctx[1]*al + p*v0.y;
        ctx[2] = ctx[2]*al + p*v0.z; ctx[3] = ctx[3]*al + p*v0.w;
        ctx[4] = ctx[4]*al + p*v1.x; ctx[5] = ctx[5]*al + p*v1.y;
        ctx[6] = ctx[6]*al + p*v1.z; ctx[7] = ctx[7]*al + p*v1.w;
        m_run = mnew;
    }
    int base = (sr * 8 + lo) * 10;
    red[base] = m_run; red[base + 1] = l_run;
    #pragma unroll
    for (int c = 0; c < 8; ++c) red[base + 2 + c] = ctx[c];
    __syncthreads();
    if (tid < 64) {
        int h = tid >> 3, c2 = tid & 7;
        float M = -1e30f;
        for (int r = 0; r < 32; ++r) M = fmaxf(M, red[(r * 8 + h) * 10]);
        float L = 0.f, CT = 0.f;
        for (int r = 0; r < 32; ++r) {
            float e = expf(red[(r * 8 + h) * 10] - M);
            L += red[(r * 8 + h) * 10 + 1] * e;
            CT += red[(r * 8 + h) * 10 + 2 + c2] * e;
        }
        float* dst = ws + WS_ATT + ((i * NCH + chk) * 8 + h) * 10;
        if (c2 == 0) { dst[0] = M; dst[1] = L; }
        dst[2 + c2] = CT;
    }
}

// ---------------- Kernel C (fallback): k/v + flash partials, reads m -------
__global__ __launch_bounds__(256) void kC(const float* __restrict__ m,
                                          const float* __restrict__ mask,
                                          const float* __restrict__ gamma,
                                          const float* __restrict__ beta,
                                          const float* __restrict__ Wk,
                                          const float* __restrict__ Wv,
                                          float* __restrict__ ws) {
    int bx = blockIdx.x;
    int i = bx >> 3, chk = bx & 7;
    int tid = threadIdx.x;
    __shared__ float mnT[32 * 68];
    __shared__ float Wk_s[8 * 68], Wv_s[8 * 68];
    __shared__ float k_s[32 * 9], v_s[32 * 9];
    __shared__ float q_s[64];
    __shared__ float red[32 * 8 * 10];
    const float* stats = ws + WS_STATS;

    if (tid < 64) q_s[tid] = ws[WS_Q + i * 64 + tid];
    for (int idx = tid; idx < 512; idx += 256) {
        int r = idx >> 6, c = idx & 63;
        Wk_s[r * 68 + c] = Wk[idx];
        Wv_s[r * 68 + c] = Wv[idx];
    }
    int sr = tid >> 3;
    int lo = tid & 7;
    float m_run = -1e30f, l_run = 0.f, ctx[8];
    #pragma unroll
    for (int z = 0; z < 8; ++z) ctx[z] = 0.f;
    __syncthreads();

    for (int t = 0; t < 8; ++t) {
        int sbase = chk * CHUNK + t * 32;
        for (int idx = tid; idx < 512; idx += 256) {
            int r = idx >> 4, c4 = idx & 15;
            int s = sbase + r;
            float4 x4 = *(const float4*)&m[((size_t)s * IDIM + i) * 64 + c4 * 4];
            float4 g4 = *(const float4*)&gamma[c4 * 4];
            float4 b4 = *(const float4*)&beta[c4 * 4];
            float2 st = *(const float2*)&stats[((size_t)i * SDIM + s) * 2];
            float4 mn;
            mn.x = (x4.x - st.x) * st.y * g4.x + b4.x;
            mn.y = (x4.y - st.x) * st.y * g4.y + b4.y;
            mn.z = (x4.z - st.x) * st.y * g4.z + b4.z;
            mn.w = (x4.w - st.x) * st.y * g4.w + b4.w;
            *(float4*)&mnT[r * 68 + c4 * 4] = mn;
        }
        __syncthreads();
        {
            float accK = 0.f, accV = 0.f;
            #pragma unroll
            for (int c4 = 0; c4 < 16; ++c4) {
                float4 a  = *(const float4*)&mnT[sr * 68 + c4 * 4];
                float4 wk = *(const float4*)&Wk_s[lo * 68 + c4 * 4];
                float4 wv = *(const float4*)&Wv_s[lo * 68 + c4 * 4];
                accK += a.x * wk.x + a.y * wk.y + a.z * wk.z + a.w * wk.w;
                accV += a.x * wv.x + a.y * wv.y + a.z * wv.z + a.w * wv.w;
            }
            k_s[sr * 9 + lo] = accK;
            v_s[sr * 9 + lo] = accV;
        }
        __syncthreads();
        {
            float lg = 0.f;
            #pragma unroll
            for (int c = 0; c < 8; ++c) lg += q_s[lo * 8 + c] * k_s[sr * 9 + c];
            float mk = mask[(sbase + sr) * IDIM + i];
            lg = (mk > 0.f) ? lg : -1e9f;
            float mnew = fmaxf(m_run, lg);
            float al = expf(m_run - mnew);
            float p  = expf(lg - mnew);
            l_run = l_run * al + p;
            #pragma unroll
            for (int c = 0; c < 8; ++c) ctx[c] = ctx[c] * al + p * v_s[sr * 9 + c];
            m_run = mnew;
        }
        __syncthreads();
    }
    int base = (sr * 8 + lo) * 10;
    red[base] = m_run; red[base + 1] = l_run;
    #pragma unroll
    for (int c = 0; c < 8; ++c) red[base + 2 + c] = ctx[c];
    __syncthreads();
    if (tid < 64) {
        int h = tid >> 3, c2 = tid & 7;
        float M = -1e30f;
        for (int r = 0; r < 32; ++r) M = fmaxf(M, red[(r * 8 + h) * 10]);
        float L = 0.f, CT = 0.f;
        for (int r = 0; r < 32; ++r) {
            float e = expf(red[(r * 8 + h) * 10] - M);
            L += red[(r * 8 + h) * 10 + 1] * e;
            CT += red[(r * 8 + h) * 10 + 2 + c2] * e;
        }
        float* dst = ws + WS_ATT + ((i * NCH + chk) * 8 + h) * 10;
        if (c2 == 0) { dst[0] = M; dst[1] = L; }
        dst[2 + c2] = CT;
    }
}

// ---------------- Kernel E: ctx-merge + gate + output GEMMs ----------------
// b-operand forced onto the scalar pipe via inline-asm s_load_dwordx16.
// Tile-major grid: consecutive blocks stream adjacent m/out segments.
__global__ __launch_bounds__(256, 8) void kE(const float* __restrict__ m,
                                             const float* __restrict__ gamma,
                                             const float* __restrict__ beta,
                                             const float* __restrict__ bg,
                                             const float* __restrict__ bo,
                                             const float* __restrict__ ws,
                                             float* __restrict__ out) {
    int bx = blockIdx.x;
    int tile = bx / IDIM;        // 0..31
    int i = bx - tile * IDIM;    // 0..383
    int tid = threadIdx.x;
    int l = tid & 63;
    int wv16 = __builtin_amdgcn_readfirstlane((tid >> 6) << 4);  // wave col base
    __shared__ float mnT[64 * 68];
    __shared__ float ctx_s[64];
    const float* stats = ws + WS_STATS;
    int s0 = tile * 64;

    // fold kD: merge chunk partials -> ctx (per-block redundant, trivial)
    if (tid < 64) {
        int h = tid >> 3, c2 = tid & 7;
        float M = -1e30f;
        #pragma unroll
        for (int c = 0; c < NCH; ++c)
            M = fmaxf(M, ws[WS_ATT + ((i * NCH + c) * 8 + h) * 10]);
        float L = 0.f, CT = 0.f;
        #pragma unroll
        for (int c = 0; c < NCH; ++c) {
            const float* src = ws + WS_ATT + ((i * NCH + c) * 8 + h) * 10;
            float e = expf(src[0] - M);
            L += src[1] * e;
            CT += src[2 + c2] * e;
        }
        ctx_s[tid] = CT / L;
    }
    // stage m_norm tile (64 rows)
    for (int idx = tid; idx < 1024; idx += 256) {
        int r = idx >> 4, c4 = idx & 15;
        int s = s0 + r;
        float4 x4 = *(const float4*)&m[((size_t)s * IDIM + i) * 64 + c4 * 4];
        float4 g4 = *(const float4*)&gamma[c4 * 4];
        float4 b4 = *(const float4*)&beta[c4 * 4];
        float2 st = *(const float2*)&stats[((size_t)i * SDIM + s) * 2];
        float4 mn;
        mn.x = (x4.x - st.x) * st.y * g4.x + b4.x;
        mn.y = (x4.y - st.x) * st.y * g4.y + b4.y;
        mn.z = (x4.z - st.x) * st.y * g4.z + b4.z;
        mn.w = (x4.w - st.x) * st.y * g4.w + b4.w;
        *(float4*)&mnT[r * 68 + c4 * 4] = mn;
    }
    __syncthreads();

    float z[16];
    #pragma unroll
    for (int jj = 0; jj < 16; ++jj) z[jj] = 0.f;
    const float* aP = &mnT[l * 68];

    // GEMM1: z = mn @ Wg^T  (b via scalar s_load_dwordx16)
    {
        const float* Bg = ws + WS_WGT + wv16;
        #pragma unroll 1
        for (int c4 = 0; c4 < 16; ++c4) {
            float4 a0 = *(const float4*)(aP + c4 * 4);
            const float* bp = Bg + c4 * 256;
            sf16 b0, b1;
            asm volatile("s_load_dwordx16 %0, %2, 0x0\n\t"
                         "s_load_dwordx16 %1, %2, 0x100\n\t"
                         "s_waitcnt lgkmcnt(0)"
                         : "=&s"(b0), "=&s"(b1) : "s"(bp));
            #pragma unroll
            for (int jj = 0; jj < 16; ++jj) z[jj] += a0.x * b0[jj];
            #pragma unroll
            for (int jj = 0; jj < 16; ++jj) z[jj] += a0.y * b1[jj];
            sf16 b2, b3;
            asm volatile("s_load_dwordx16 %0, %2, 0x200\n\t"
                         "s_load_dwordx16 %1, %2, 0x300\n\t"
                         "s_waitcnt lgkmcnt(0)"
                         : "=&s"(b2), "=&s"(b3) : "s"(bp));
            #pragma unroll
            for (int jj = 0; jj < 16; ++jj) z[jj] += a0.z * b2[jj];
            #pragma unroll
            for (int jj = 0; jj < 16; ++jj) z[jj] += a0.w * b3[jj];
        }
    }
    __syncthreads();   // GEMM1 LDS reads done before overwriting with o

    // gate: o = ctx * sigmoid(z + bg) -> park in own 16-col slab
    #pragma unroll
    for (int q = 0; q < 4; ++q) {
        float4 cv = *(const float4*)&ctx_s[wv16 + q * 4];
        float4 gv = *(const float4*)&bg[wv16 + q * 4];
        float o0 = cv.x / (1.f + expf(-(z[q*4+0] + gv.x)));
        float o1 = cv.y / (1.f + expf(-(z[q*4+1] + gv.y)));
        float o2 = cv.z / (1.f + expf(-(z[q*4+2] + gv.z)));
        float o3 = cv.w / (1.f + expf(-(z[q*4+3] + gv.w)));
        float4 t0 = {o0, o1, o2, o3};
        *(float4*)&mnT[l * 68 + wv16 + q * 4] = t0;
    }
    #pragma unroll
    for (int jj = 0; jj < 16; ++jj) z[jj] = 0.f;
    __syncthreads();

    // GEMM2: w = o @ Wo^T  (b via scalar s_load_dwordx16)
    {
        const float* Bo = ws + WS_WOT + wv16;
        #pragma unroll 1
        for (int c4 = 0; c4 < 16; ++c4) {
            float4 a0 = *(const float4*)(aP + c4 * 4);
            const float* bp = Bo + c4 * 256;
            sf16 b0, b1;
            asm volatile("s_load_dwordx16 %0, %2, 0x0\n\t"
                         "s_load_dwordx16 %1, %2, 0x100\n\t"
                         "s_waitcnt lgkmcnt(0)"
                         : "=&s"(b0), "=&s"(b1) : "s"(bp));
            #pragma unroll
            for (int jj = 0; jj < 16; ++jj) z[jj] += a0.x * b0[jj];
            #pragma unroll
            for (int jj = 0; jj < 16; ++jj) z[jj] += a0.y * b1[jj];
            sf16 b2, b3;
            asm volatile("s_load_dwordx16 %0, %2, 0x200\n\t"
                         "s_load_dwordx16 %1, %2, 0x300\n\t"
                         "s_waitcnt lgkmcnt(0)"
                         : "=&s"(b2), "=&s"(b3) : "s"(bp));
            #pragma unroll
            for (int jj = 0; jj < 16; ++jj) z[jj] += a0.z * b2[jj];
            #pragma unroll
            for (int jj = 0; jj < 16; ++jj) z[jj] += a0.w * b3[jj];
        }
    }
    __syncthreads();   // GEMM2 LDS reads done before overwriting with out

    #pragma unroll
    for (int q = 0; q < 4; ++q) {
        float4 ov = *(const float4*)&bo[wv16 + q * 4];
        float4 t0 = {z[q*4+0] + ov.x, z[q*4+1] + ov.y,
                     z[q*4+2] + ov.z, z[q*4+3] + ov.w};
        *(float4*)&mnT[l * 68 + wv16 + q * 4] = t0;
    }
    __syncthreads();

    // coalesced store: 16 lanes cover one row's 256B
    for (int idx = tid; idx < 1024; idx += 256) {
        int r = idx >> 4, c4 = idx & 15;
        float4 v = *(const float4*)&mnT[r * 68 + c4 * 4];
        *(float4*)&out[((size_t)(s0 + r) * IDIM + i) * 64 + c4 * 4] = v;
    }
}

extern "C" void kernel_launch(void* const* d_in, const int* in_sizes, int n_in,
                              void* d_out, int out_size, void* d_ws, size_t ws_size,
                              hipStream_t stream) {
    const float* m    = (const float*)d_in[0];
    const float* mask = (const float*)d_in[1];
    const float* gam  = (const float*)d_in[2];
    const float* bet  = (const float*)d_in[3];
    const float* Wq   = (const float*)d_in[4];
    const float* Wk   = (const float*)d_in[5];
    const float* Wv   = (const float*)d_in[6];
    const float* Wg   = (const float*)d_in[7];
    const float* bg   = (const float*)d_in[8];
    const float* Wo   = (const float*)d_in[9];
    const float* bo   = (const float*)d_in[10];
    float* out = (float*)d_out;
    float* ws  = (float*)d_ws;
    (void)in_sizes; (void)n_in; (void)out_size;

    size_t need_fused = (size_t)(WS_KV + (size_t)IDIM * SDIM * 16) * sizeof(float);
    bool fused = ws_size >= need_fused;

    if (fused) {
        kA2<true><<<IDIM * NCH, 256, 0, stream>>>(m, mask, gam, bet, Wk, Wv, Wg, Wo, ws);
        kC2<<<IDIM * NCH, 256, 0, stream>>>(mask, Wq, ws);
    } else {
        kA2<false><<<IDIM * NCH, 256, 0, stream>>>(m, mask, gam, bet, Wk, Wv, Wg, Wo, ws);
        kB<<<IDIM, 64, 0, stream>>>(Wq, ws);
        kC<<<IDIM * NCH, 256, 0, stream>>>(m, mask, gam, bet, Wk, Wv, ws);
    }
    kE<<<IDIM * (SDIM / 64), 256, 0, stream>>>(m, gam, bet, bg, bo, ws, out);
}